// Round 10
// baseline (540.868 us; speedup 1.0000x reference)
//
#include <hip/hip_runtime.h>

constexpr int kB  = 512;
constexpr int kV  = 6890;
constexpr int kJ  = 24;
constexpr int kD  = kV * 3;   // 20670
constexpr int kNB = 10;
constexpr int kNF = 93;

// ---------------------------------------------------------------------------
// KA: batch-independent joint-regressor folding, v-split x4 + atomicAdd.
// grid(72,4): blockIdx.x = (j,k), blockIdx.y = v-partition. block(256).
// js/jt zeroed by hipMemsetAsync before launch.
// ---------------------------------------------------------------------------
__global__ __launch_bounds__(256) void kA_js(
    const float* __restrict__ Jreg, const float* __restrict__ shapedirs,
    const float* __restrict__ v_template, float* __restrict__ js,
    float* __restrict__ jt) {
  int jk = blockIdx.x;
  int j = jk / 3, k = jk % 3;
  int tid = threadIdx.x;
  float acc[kNB];
  float accT = 0.f;
#pragma unroll
  for (int nb = 0; nb < kNB; ++nb) acc[nb] = 0.f;
  for (int v = blockIdx.y * 256 + tid; v < kV; v += 1024) {
    float w = Jreg[(size_t)j * kV + v];
    const float* srow = shapedirs + (size_t)(v * 3 + k) * kNB;
    accT += w * v_template[v * 3 + k];
#pragma unroll
    for (int nb = 0; nb < kNB; ++nb) acc[nb] += w * srow[nb];
  }
#pragma unroll
  for (int nb = 0; nb < kNB; ++nb)
#pragma unroll
    for (int off = 32; off > 0; off >>= 1)
      acc[nb] += __shfl_down(acc[nb], off, 64);
#pragma unroll
  for (int off = 32; off > 0; off >>= 1) accT += __shfl_down(accT, off, 64);
  __shared__ float red[4][11];
  int wave = tid >> 6, lane = tid & 63;
  if (lane == 0) {
#pragma unroll
    for (int nb = 0; nb < kNB; ++nb) red[wave][nb] = acc[nb];
    red[wave][10] = accT;
  }
  __syncthreads();
  if (tid == 0) {
#pragma unroll
    for (int nb = 0; nb < kNB; ++nb)
      atomicAdd(&js[jk * kNB + nb],
                red[0][nb] + red[1][nb] + red[2][nb] + red[3][nb]);
    atomicAdd(&jt[jk], red[0][10] + red[1][10] + red[2][10] + red[3][10]);
  }
}

// ---------------------------------------------------------------------------
// KC: per-batch everything-small. Quat features -> pfT ([f][b] transposed),
// Rodrigues R (regs), Jp = JT + JS*betas (LDS), kinematic chain by tree
// level, G_skin, J_transformed. grid(kB), block(64) = 1 wave.
// ---------------------------------------------------------------------------
__global__ __launch_bounds__(64) void kC_batch(
    const float* __restrict__ pose, const float* __restrict__ betas,
    const float* __restrict__ trans, const float* __restrict__ js,
    const float* __restrict__ jt, float* __restrict__ pfT,
    float* __restrict__ Gskin, float* __restrict__ out_Jt) {
  const int parent[24] = {-1, 0, 0, 0, 1, 2, 3, 4, 5, 6, 7, 8,
                          9, 9, 9, 12, 13, 14, 16, 17, 18, 19, 20, 21};
  const int depth[24] = {0, 1, 1, 1, 2, 2, 2, 3, 3, 3, 4, 4,
                         4, 4, 4, 5, 5, 5, 6, 6, 7, 7, 8, 8};
  int b = blockIdx.x;
  int j = threadIdx.x;
  __shared__ float G[24][12];
  __shared__ float Jp_s[24][3];
  float R[9];
  if (j < 24) {
    float t0 = pose[b * 72 + 3 * j + 0];
    float t1 = pose[b * 72 + 3 * j + 1];
    float t2 = pose[b * 72 + 3 * j + 2];
    float a0 = t0 + 1e-8f, a1 = t1 + 1e-8f, a2 = t2 + 1e-8f;
    float angle = sqrtf(a0 * a0 + a1 * a1 + a2 * a2);
    float inv = 1.0f / angle;
    float h = 0.5f * angle;
    float c = cosf(h), s = sinf(h);
    float x = s * t0 * inv, y = s * t1 * inv, z = s * t2 * inv, w = c;
    if (j >= 1) {
      int f = 4 * (j - 1);
      pfT[(size_t)(f + 0) * kB + b] = x;
      pfT[(size_t)(f + 1) * kB + b] = y;
      pfT[(size_t)(f + 2) * kB + b] = z;
      pfT[(size_t)(f + 3) * kB + b] = c - 1.0f;
    } else {
      pfT[(size_t)92 * kB + b] = betas[b * kNB + 1];
    }
    float xx = x * x, yy = y * y, zz = z * z;
    float wx = w * x, wy = w * y, wz = w * z;
    float xy = x * y, xz = x * z, yz = y * z;
    R[0] = 1.f - 2.f * (yy + zz); R[1] = 2.f * (xy - wz); R[2] = 2.f * (xz + wy);
    R[3] = 2.f * (xy + wz); R[4] = 1.f - 2.f * (xx + zz); R[5] = 2.f * (yz - wx);
    R[6] = 2.f * (xz - wy); R[7] = 2.f * (yz + wx); R[8] = 1.f - 2.f * (xx + yy);
    float bet[kNB];
#pragma unroll
    for (int nb = 0; nb < kNB; ++nb) bet[nb] = betas[b * kNB + nb];
#pragma unroll
    for (int k = 0; k < 3; ++k) {
      float a = jt[j * 3 + k];
      const float* jr = js + (size_t)(j * 3 + k) * kNB;
#pragma unroll
      for (int nb = 0; nb < kNB; ++nb) a += jr[nb] * bet[nb];
      Jp_s[j][k] = a;
    }
  }
  __syncthreads();
  float tl[3];
  if (j < 24) {
    int p = parent[j];
#pragma unroll
    for (int k = 0; k < 3; ++k)
      tl[k] = (p >= 0) ? (Jp_s[j][k] - Jp_s[p][k]) : Jp_s[j][k];
    if (j == 0) {
#pragma unroll
      for (int r = 0; r < 3; ++r) {
        G[0][r * 4 + 0] = R[r * 3 + 0];
        G[0][r * 4 + 1] = R[r * 3 + 1];
        G[0][r * 4 + 2] = R[r * 3 + 2];
        G[0][r * 4 + 3] = tl[r];
      }
    }
  }
  __syncthreads();
  for (int lev = 1; lev <= 8; ++lev) {
    if (j < 24 && depth[j] == lev) {
      int p = parent[j];
      float nG[12];
#pragma unroll
      for (int r = 0; r < 3; ++r) {
        float g0 = G[p][r * 4 + 0], g1 = G[p][r * 4 + 1];
        float g2 = G[p][r * 4 + 2], g3 = G[p][r * 4 + 3];
        nG[r * 4 + 0] = g0 * R[0] + g1 * R[3] + g2 * R[6];
        nG[r * 4 + 1] = g0 * R[1] + g1 * R[4] + g2 * R[7];
        nG[r * 4 + 2] = g0 * R[2] + g1 * R[5] + g2 * R[8];
        nG[r * 4 + 3] = g0 * tl[0] + g1 * tl[1] + g2 * tl[2] + g3;
      }
#pragma unroll
      for (int e = 0; e < 12; ++e) G[j][e] = nG[e];
    }
    __syncthreads();
  }
  if (j < 24) {
    float tr[3];
#pragma unroll
    for (int k = 0; k < 3; ++k) tr[k] = trans[b * 3 + k];
#pragma unroll
    for (int k = 0; k < 3; ++k)
      out_Jt[b * 72 + j * 3 + k] = G[j][k * 4 + 3] + tr[k];
    float jp0 = Jp_s[j][0], jp1 = Jp_s[j][1], jp2 = Jp_s[j][2];
    float* gs = Gskin + b * 288 + j * 12;
#pragma unroll
    for (int r = 0; r < 3; ++r) {
      float t = G[j][r * 4 + 0] * jp0 + G[j][r * 4 + 1] * jp1 + G[j][r * 4 + 2] * jp2;
      gs[r * 4 + 0] = G[j][r * 4 + 0];
      gs[r * 4 + 1] = G[j][r * 4 + 1];
      gs[r * 4 + 2] = G[j][r * 4 + 2];
      gs[r * 4 + 3] = G[j][r * 4 + 3] - t;
    }
  }
}

// ---------------------------------------------------------------------------
// K14 v5: shape+pose blend, structurally cloned from the PROVEN k5 v3
// recipe: small accumulator set (ap[8], BT=8, 4 bc groups), LDS broadcast
// operands (pfT/betas tiles), NO persistent per-thread array (posedirs
// STREAMED one scalar per f — nothing for the allocator to spill (r2),
// rematerialize (r3/r4) or strip-mine (r9: ap[32] -> VGPR=48, 10% VALUBusy,
// 191 us)). Live set ~ ap[8] + 8-float4 window + sd[10] ~ 60 regs = k5 v3's
// regime. f-loop #pragma unroll 4 (k5's proven setting).
// grid(81, 16), block(256). LDS 13.4 KB.
// ---------------------------------------------------------------------------
__global__ __launch_bounds__(256) void k14_fused(
    const float* __restrict__ shapedirs, const float* __restrict__ posedirs,
    const float* __restrict__ v_template, const float* __restrict__ betas,
    const float* __restrict__ pfT, float* __restrict__ out_vshaped,
    float* __restrict__ out_vposed) {
  __shared__ __align__(16) float pfs[kNF * 32];  // [f][c], rows 128B apart
  __shared__ float bets[32 * 12];                // [c][nb], stride 12
  const int tid = threadIdx.x;
  const int d = blockIdx.x * 256 + tid;
  const bool active = d < kD;
  const int dl = active ? d : (kD - 1);
  const int b0 = blockIdx.y * 32;

  // stage pfT tile [93][32] and betas tile [32][10], coalesced
  for (int i = tid; i < kNF * 32; i += 256) {
    int f = i >> 5, c = i & 31;
    pfs[i] = pfT[(size_t)f * kB + b0 + c];
  }
  for (int i = tid; i < 32 * kNB; i += 256) {
    int c = i / kNB, nb = i - c * kNB;
    bets[c * 12 + nb] = betas[(size_t)(b0 + c) * kNB + nb];
  }

  float sd[kNB];
#pragma unroll
  for (int k = 0; k < kNB; ++k) sd[k] = shapedirs[(size_t)dl * kNB + k];
  const float vt = v_template[dl];
  const float* prow = posedirs + (size_t)dl * kNF;

  __syncthreads();

#pragma unroll 1
  for (int bc = 0; bc < 4; ++bc) {
    const int bb = b0 + bc * 8;

    // betas pass: vshaped out, ap init (8 accumulators, static indices)
    float ap[8];
#pragma unroll
    for (int t = 0; t < 8; ++t) {
      const float* be = bets + (bc * 8 + t) * 12;  // LDS broadcast
      float a = vt;
#pragma unroll
      for (int k = 0; k < kNB; ++k) a += sd[k] * be[k];
      ap[t] = a;
      if (active) out_vshaped[(size_t)(bb + t) * kD + d] = a;
    }

    // f-loop: stream pd scalar (global, L1-served), 2 LDS float4 broadcasts,
    // 8 FMAs per f. Same shape as k5 v3's j-loop (1 scalar + 3 float4 + 12).
#pragma unroll 4
    for (int f = 0; f < kNF; ++f) {
      float pdf = prow[f];
      const float4* q4 = (const float4*)(pfs + f * 32);
      float4 qa = q4[bc * 2 + 0];
      float4 qb = q4[bc * 2 + 1];
      ap[0] += pdf * qa.x; ap[1] += pdf * qa.y;
      ap[2] += pdf * qa.z; ap[3] += pdf * qa.w;
      ap[4] += pdf * qb.x; ap[5] += pdf * qb.y;
      ap[6] += pdf * qb.z; ap[7] += pdf * qb.w;
    }

    if (active) {
#pragma unroll
      for (int t = 0; t < 8; ++t)
        out_vposed[(size_t)(bb + t) * kD + d] = ap[t];
    }
  }
}

// ---------------------------------------------------------------------------
// K5 v3 (r7-proven, 77 -> <74 us): LBS skinning with LDS-staged Gskin.
// 8 batches of Gskin (9.2 KB) staged coalesced once per block; j-loop feeds
// from ds_read_b128 broadcasts. Live set ~60 floats -> no allocator
// pathology. vposed prefetched before the j-loop. grid(27, 64), block(256).
// ---------------------------------------------------------------------------
__global__ __launch_bounds__(256) void k5_skin(
    const float* __restrict__ weights, const float* __restrict__ Gskin,
    const float* __restrict__ trans, const float* __restrict__ vposed,
    float* __restrict__ out_v) {
  __shared__ __align__(16) float Gs[8 * 288];  // 9216 B
  int tid = threadIdx.x;
  int v = blockIdx.x * 256 + tid;
  bool active = v < kV;
  int vl = active ? v : (kV - 1);
  float w[kJ];
#pragma unroll
  for (int j = 0; j < kJ; ++j) w[j] = weights[(size_t)vl * kJ + j];
  int b0 = blockIdx.y * 8;
  {
    const float* src = Gskin + (size_t)b0 * 288;
#pragma unroll
    for (int i = 0; i < 9; ++i) Gs[i * 256 + tid] = src[i * 256 + tid];
  }
  __syncthreads();
#pragma unroll 1
  for (int bi = 0; bi < 8; ++bi) {
    int b = b0 + bi;
    size_t base = (size_t)b * kD + (size_t)vl * 3;
    float q0 = vposed[base + 0];
    float q1 = vposed[base + 1];
    float q2 = vposed[base + 2];
    float tr0 = trans[b * 3 + 0];
    float tr1 = trans[b * 3 + 1];
    float tr2 = trans[b * 3 + 2];
    const float4* Gt = (const float4*)(Gs + bi * 288);
    float T0 = 0.f, T1 = 0.f, T2 = 0.f, T3 = 0.f;
    float T4 = 0.f, T5 = 0.f, T6 = 0.f, T7 = 0.f;
    float T8 = 0.f, T9 = 0.f, T10 = 0.f, T11 = 0.f;
#pragma unroll 4
    for (int j = 0; j < kJ; ++j) {
      float wj = w[j];
      float4 ga = Gt[j * 3 + 0];  // broadcast ds_read_b128
      float4 gb = Gt[j * 3 + 1];
      float4 gc = Gt[j * 3 + 2];
      T0 += wj * ga.x; T1 += wj * ga.y; T2 += wj * ga.z; T3 += wj * ga.w;
      T4 += wj * gb.x; T5 += wj * gb.y; T6 += wj * gb.z; T7 += wj * gb.w;
      T8 += wj * gc.x; T9 += wj * gc.y; T10 += wj * gc.z; T11 += wj * gc.w;
    }
    if (active) {
      out_v[base + 0] = T0 * q0 + T1 * q1 + T2 * q2 + T3 + tr0;
      out_v[base + 1] = T4 * q0 + T5 * q1 + T6 * q2 + T7 + tr1;
      out_v[base + 2] = T8 * q0 + T9 * q1 + T10 * q2 + T11 + tr2;
    }
  }
}

// ---------------------------------------------------------------------------
extern "C" void kernel_launch(void* const* d_in, const int* in_sizes, int n_in,
                              void* d_out, int out_size, void* d_ws,
                              size_t ws_size, hipStream_t stream) {
  const float* pose       = (const float*)d_in[0];
  const float* betas      = (const float*)d_in[1];
  const float* trans      = (const float*)d_in[2];
  const float* v_template = (const float*)d_in[3];
  const float* shapedirs  = (const float*)d_in[4];
  const float* posedirs   = (const float*)d_in[5];
  const float* Jreg       = (const float*)d_in[6];
  const float* weights    = (const float*)d_in[7];

  float* out = (float*)d_out;
  float* out_v       = out;
  float* out_vposed  = out + (size_t)kB * kD;
  float* out_vshaped = out + 2 * (size_t)kB * kD;
  float* out_Jt      = out + 3 * (size_t)kB * kD;

  float* wsf   = (float*)d_ws;
  float* pfT   = wsf;                   // kNF*kB
  float* Gskin = pfT + kNF * kB;        // kB*288
  float* js    = Gskin + kB * 288;      // 72*10
  float* jt    = js + 72 * kNB;         // 72

  // zero the atomic accumulators (js: 720 floats, jt: 72 floats, contiguous)
  hipMemsetAsync(js, 0, (72 * kNB + 72) * sizeof(float), stream);

  hipLaunchKernelGGL(kA_js, dim3(72, 4), dim3(256), 0, stream, Jreg, shapedirs,
                     v_template, js, jt);
  hipLaunchKernelGGL(kC_batch, dim3(kB), dim3(64), 0, stream, pose, betas,
                     trans, js, jt, pfT, Gskin, out_Jt);
  hipLaunchKernelGGL(k14_fused, dim3((kD + 255) / 256, 16), dim3(256), 0,
                     stream, shapedirs, posedirs, v_template, betas, pfT,
                     out_vshaped, out_vposed);
  hipLaunchKernelGGL(k5_skin, dim3((kV + 255) / 256, 64), dim3(256), 0, stream,
                     weights, Gskin, trans, out_vposed, out_v);
}

// Round 11
// 392.733 us; speedup vs baseline: 1.3772x; 1.3772x over previous
//
#include <hip/hip_runtime.h>

constexpr int kB  = 512;
constexpr int kV  = 6890;
constexpr int kJ  = 24;
constexpr int kD  = kV * 3;   // 20670
constexpr int kNB = 10;
constexpr int kNF = 93;

// ---------------------------------------------------------------------------
// KA: batch-independent joint-regressor folding, v-split x4 + atomicAdd.
// grid(72,4): blockIdx.x = (j,k), blockIdx.y = v-partition. block(256).
// js/jt zeroed by hipMemsetAsync before launch.
// ---------------------------------------------------------------------------
__global__ __launch_bounds__(256) void kA_js(
    const float* __restrict__ Jreg, const float* __restrict__ shapedirs,
    const float* __restrict__ v_template, float* __restrict__ js,
    float* __restrict__ jt) {
  int jk = blockIdx.x;
  int j = jk / 3, k = jk % 3;
  int tid = threadIdx.x;
  float acc[kNB];
  float accT = 0.f;
#pragma unroll
  for (int nb = 0; nb < kNB; ++nb) acc[nb] = 0.f;
  for (int v = blockIdx.y * 256 + tid; v < kV; v += 1024) {
    float w = Jreg[(size_t)j * kV + v];
    const float* srow = shapedirs + (size_t)(v * 3 + k) * kNB;
    accT += w * v_template[v * 3 + k];
#pragma unroll
    for (int nb = 0; nb < kNB; ++nb) acc[nb] += w * srow[nb];
  }
#pragma unroll
  for (int nb = 0; nb < kNB; ++nb)
#pragma unroll
    for (int off = 32; off > 0; off >>= 1)
      acc[nb] += __shfl_down(acc[nb], off, 64);
#pragma unroll
  for (int off = 32; off > 0; off >>= 1) accT += __shfl_down(accT, off, 64);
  __shared__ float red[4][11];
  int wave = tid >> 6, lane = tid & 63;
  if (lane == 0) {
#pragma unroll
    for (int nb = 0; nb < kNB; ++nb) red[wave][nb] = acc[nb];
    red[wave][10] = accT;
  }
  __syncthreads();
  if (tid == 0) {
#pragma unroll
    for (int nb = 0; nb < kNB; ++nb)
      atomicAdd(&js[jk * kNB + nb],
                red[0][nb] + red[1][nb] + red[2][nb] + red[3][nb]);
    atomicAdd(&jt[jk], red[0][10] + red[1][10] + red[2][10] + red[3][10]);
  }
}

// ---------------------------------------------------------------------------
// KC: per-batch everything-small. Quat features -> pfT ([f][b] transposed),
// Rodrigues R (regs), Jp = JT + JS*betas (LDS), kinematic chain by tree
// level, G_skin, J_transformed. grid(kB), block(64) = 1 wave.
// ---------------------------------------------------------------------------
__global__ __launch_bounds__(64) void kC_batch(
    const float* __restrict__ pose, const float* __restrict__ betas,
    const float* __restrict__ trans, const float* __restrict__ js,
    const float* __restrict__ jt, float* __restrict__ pfT,
    float* __restrict__ Gskin, float* __restrict__ out_Jt) {
  const int parent[24] = {-1, 0, 0, 0, 1, 2, 3, 4, 5, 6, 7, 8,
                          9, 9, 9, 12, 13, 14, 16, 17, 18, 19, 20, 21};
  const int depth[24] = {0, 1, 1, 1, 2, 2, 2, 3, 3, 3, 4, 4,
                         4, 4, 4, 5, 5, 5, 6, 6, 7, 7, 8, 8};
  int b = blockIdx.x;
  int j = threadIdx.x;
  __shared__ float G[24][12];
  __shared__ float Jp_s[24][3];
  float R[9];
  if (j < 24) {
    float t0 = pose[b * 72 + 3 * j + 0];
    float t1 = pose[b * 72 + 3 * j + 1];
    float t2 = pose[b * 72 + 3 * j + 2];
    float a0 = t0 + 1e-8f, a1 = t1 + 1e-8f, a2 = t2 + 1e-8f;
    float angle = sqrtf(a0 * a0 + a1 * a1 + a2 * a2);
    float inv = 1.0f / angle;
    float h = 0.5f * angle;
    float c = cosf(h), s = sinf(h);
    float x = s * t0 * inv, y = s * t1 * inv, z = s * t2 * inv, w = c;
    if (j >= 1) {
      int f = 4 * (j - 1);
      pfT[(size_t)(f + 0) * kB + b] = x;
      pfT[(size_t)(f + 1) * kB + b] = y;
      pfT[(size_t)(f + 2) * kB + b] = z;
      pfT[(size_t)(f + 3) * kB + b] = c - 1.0f;
    } else {
      pfT[(size_t)92 * kB + b] = betas[b * kNB + 1];
    }
    float xx = x * x, yy = y * y, zz = z * z;
    float wx = w * x, wy = w * y, wz = w * z;
    float xy = x * y, xz = x * z, yz = y * z;
    R[0] = 1.f - 2.f * (yy + zz); R[1] = 2.f * (xy - wz); R[2] = 2.f * (xz + wy);
    R[3] = 2.f * (xy + wz); R[4] = 1.f - 2.f * (xx + zz); R[5] = 2.f * (yz - wx);
    R[6] = 2.f * (xz - wy); R[7] = 2.f * (yz + wx); R[8] = 1.f - 2.f * (xx + yy);
    float bet[kNB];
#pragma unroll
    for (int nb = 0; nb < kNB; ++nb) bet[nb] = betas[b * kNB + nb];
#pragma unroll
    for (int k = 0; k < 3; ++k) {
      float a = jt[j * 3 + k];
      const float* jr = js + (size_t)(j * 3 + k) * kNB;
#pragma unroll
      for (int nb = 0; nb < kNB; ++nb) a += jr[nb] * bet[nb];
      Jp_s[j][k] = a;
    }
  }
  __syncthreads();
  float tl[3];
  if (j < 24) {
    int p = parent[j];
#pragma unroll
    for (int k = 0; k < 3; ++k)
      tl[k] = (p >= 0) ? (Jp_s[j][k] - Jp_s[p][k]) : Jp_s[j][k];
    if (j == 0) {
#pragma unroll
      for (int r = 0; r < 3; ++r) {
        G[0][r * 4 + 0] = R[r * 3 + 0];
        G[0][r * 4 + 1] = R[r * 3 + 1];
        G[0][r * 4 + 2] = R[r * 3 + 2];
        G[0][r * 4 + 3] = tl[r];
      }
    }
  }
  __syncthreads();
  for (int lev = 1; lev <= 8; ++lev) {
    if (j < 24 && depth[j] == lev) {
      int p = parent[j];
      float nG[12];
#pragma unroll
      for (int r = 0; r < 3; ++r) {
        float g0 = G[p][r * 4 + 0], g1 = G[p][r * 4 + 1];
        float g2 = G[p][r * 4 + 2], g3 = G[p][r * 4 + 3];
        nG[r * 4 + 0] = g0 * R[0] + g1 * R[3] + g2 * R[6];
        nG[r * 4 + 1] = g0 * R[1] + g1 * R[4] + g2 * R[7];
        nG[r * 4 + 2] = g0 * R[2] + g1 * R[5] + g2 * R[8];
        nG[r * 4 + 3] = g0 * tl[0] + g1 * tl[1] + g2 * tl[2] + g3;
      }
#pragma unroll
      for (int e = 0; e < 12; ++e) G[j][e] = nG[e];
    }
    __syncthreads();
  }
  if (j < 24) {
    float tr[3];
#pragma unroll
    for (int k = 0; k < 3; ++k) tr[k] = trans[b * 3 + k];
#pragma unroll
    for (int k = 0; k < 3; ++k)
      out_Jt[b * 72 + j * 3 + k] = G[j][k * 4 + 3] + tr[k];
    float jp0 = Jp_s[j][0], jp1 = Jp_s[j][1], jp2 = Jp_s[j][2];
    float* gs = Gskin + b * 288 + j * 12;
#pragma unroll
    for (int r = 0; r < 3; ++r) {
      float t = G[j][r * 4 + 0] * jp0 + G[j][r * 4 + 1] * jp1 + G[j][r * 4 + 2] * jp2;
      gs[r * 4 + 0] = G[j][r * 4 + 0];
      gs[r * 4 + 1] = G[j][r * 4 + 1];
      gs[r * 4 + 2] = G[j][r * 4 + 2];
      gs[r * 4 + 3] = G[j][r * 4 + 3] - t;
    }
  }
}

// ---------------------------------------------------------------------------
// K14 v6: shape+pose blend, F-SPLIT ACROSS WAVES. Proven ingredients only:
//  - pfT/betas via SGPR wave-uniform loads (r0-proven path; readfirstlane
//    forces the per-wave f-chunk base into an SGPR so addresses scalarize);
//  - small per-thread state: pd[24] + ap[8] (~60 regs, k5-v3 regime — no
//    spill(r2)/remat(r3,r4)/strip-mine(r9)); NO per-lane global loads in
//    the inner loop (r10's 347us failure);
//  - all pd/ap indices compile-time (rule #20).
// Block = 4 waves x 64 d-rows; wave w owns f in [24w, 24w+24). Per-wave
// serial s_load chain is 4x shorter than the r0 form (<=192 floats/bc vs
// 744). Partials reduced via 6 KB LDS; wave 0 adds betas part + stores.
// grid(323, 16), block(256).
// ---------------------------------------------------------------------------
__global__ __launch_bounds__(256) void k14_fused(
    const float* __restrict__ shapedirs, const float* __restrict__ posedirs,
    const float* __restrict__ v_template, const float* __restrict__ betas,
    const float* __restrict__ pfT, float* __restrict__ out_vshaped,
    float* __restrict__ out_vposed) {
  __shared__ float part[3][64][8];  // waves 1..3 partial sums, 6 KB
  const int tid = threadIdx.x;
  const int dloc = tid & 63;
  const int d = blockIdx.x * 64 + dloc;
  const bool active = d < kD;
  const int dl = active ? d : (kD - 1);
  const int wv = tid >> 6;
  // f-chunk base, forced into SGPR so pfT addresses provably scalarize
  const int wb = __builtin_amdgcn_readfirstlane(wv * 24);
  const int nfc = (kNF - wb) < 24 ? (kNF - wb) : 24;  // uniform (24,24,24,21)
  const int b0 = blockIdx.y * 32;

  // per-thread posedirs chunk (<=24 floats, registers, loaded once)
  float pd[24];
  const float* prow = posedirs + (size_t)dl * kNF + wb;
#pragma unroll
  for (int i = 0; i < 24; ++i) pd[i] = (i < nfc) ? prow[i] : 0.f;

  float sd[kNB];
  float vt = 0.f;
  if (wv == 0) {
#pragma unroll
    for (int k = 0; k < kNB; ++k) sd[k] = shapedirs[(size_t)dl * kNB + k];
    vt = v_template[dl];
  }

#pragma unroll 1
  for (int bc = 0; bc < 4; ++bc) {
    const int bb = b0 + bc * 8;

    float ap[8];
    if (wv == 0) {
      // betas pass (SGPR operands): vshaped out, ap init
#pragma unroll
      for (int t = 0; t < 8; ++t) {
        const float* be = betas + (size_t)(bb + t) * kNB;  // wave-uniform
        float a = vt;
#pragma unroll
        for (int k = 0; k < kNB; ++k) a += sd[k] * be[k];
        ap[t] = a;
        if (active) out_vshaped[(size_t)(bb + t) * kD + d] = a;
      }
    } else {
#pragma unroll
      for (int t = 0; t < 8; ++t) ap[t] = 0.f;
    }

    // f-chunk: pfT row via SGPR wave-uniform load, pd from registers.
#pragma unroll
    for (int fi = 0; fi < 24; ++fi) {
      if (wb + fi < kNF) {  // uniform guard (scalar branch; wave3 skips 3)
        const float* q = pfT + (size_t)(wb + fi) * kB + bb;  // wave-uniform
        float pdf = pd[fi];
        ap[0] += pdf * q[0]; ap[1] += pdf * q[1];
        ap[2] += pdf * q[2]; ap[3] += pdf * q[3];
        ap[4] += pdf * q[4]; ap[5] += pdf * q[5];
        ap[6] += pdf * q[6]; ap[7] += pdf * q[7];
      }
    }

    // reduce partials across waves
    if (wv != 0) {
#pragma unroll
      for (int t = 0; t < 8; ++t) part[wv - 1][dloc][t] = ap[t];
    }
    __syncthreads();
    if (wv == 0 && active) {
#pragma unroll
      for (int t = 0; t < 8; ++t) {
        float s = ap[t] + part[0][dloc][t] + part[1][dloc][t] +
                  part[2][dloc][t];
        out_vposed[(size_t)(bb + t) * kD + d] = s;
      }
    }
    __syncthreads();  // protect part[] reuse next bc
  }
}

// ---------------------------------------------------------------------------
// K5 v3 (r7-proven, 77 -> <74 us): LBS skinning with LDS-staged Gskin.
// 8 batches of Gskin (9.2 KB) staged coalesced once per block; j-loop feeds
// from ds_read_b128 broadcasts. Live set ~60 floats -> no allocator
// pathology. vposed prefetched before the j-loop. grid(27, 64), block(256).
// ---------------------------------------------------------------------------
__global__ __launch_bounds__(256) void k5_skin(
    const float* __restrict__ weights, const float* __restrict__ Gskin,
    const float* __restrict__ trans, const float* __restrict__ vposed,
    float* __restrict__ out_v) {
  __shared__ __align__(16) float Gs[8 * 288];  // 9216 B
  int tid = threadIdx.x;
  int v = blockIdx.x * 256 + tid;
  bool active = v < kV;
  int vl = active ? v : (kV - 1);
  float w[kJ];
#pragma unroll
  for (int j = 0; j < kJ; ++j) w[j] = weights[(size_t)vl * kJ + j];
  int b0 = blockIdx.y * 8;
  {
    const float* src = Gskin + (size_t)b0 * 288;
#pragma unroll
    for (int i = 0; i < 9; ++i) Gs[i * 256 + tid] = src[i * 256 + tid];
  }
  __syncthreads();
#pragma unroll 1
  for (int bi = 0; bi < 8; ++bi) {
    int b = b0 + bi;
    size_t base = (size_t)b * kD + (size_t)vl * 3;
    float q0 = vposed[base + 0];
    float q1 = vposed[base + 1];
    float q2 = vposed[base + 2];
    float tr0 = trans[b * 3 + 0];
    float tr1 = trans[b * 3 + 1];
    float tr2 = trans[b * 3 + 2];
    const float4* Gt = (const float4*)(Gs + bi * 288);
    float T0 = 0.f, T1 = 0.f, T2 = 0.f, T3 = 0.f;
    float T4 = 0.f, T5 = 0.f, T6 = 0.f, T7 = 0.f;
    float T8 = 0.f, T9 = 0.f, T10 = 0.f, T11 = 0.f;
#pragma unroll 4
    for (int j = 0; j < kJ; ++j) {
      float wj = w[j];
      float4 ga = Gt[j * 3 + 0];  // broadcast ds_read_b128
      float4 gb = Gt[j * 3 + 1];
      float4 gc = Gt[j * 3 + 2];
      T0 += wj * ga.x; T1 += wj * ga.y; T2 += wj * ga.z; T3 += wj * ga.w;
      T4 += wj * gb.x; T5 += wj * gb.y; T6 += wj * gb.z; T7 += wj * gb.w;
      T8 += wj * gc.x; T9 += wj * gc.y; T10 += wj * gc.z; T11 += wj * gc.w;
    }
    if (active) {
      out_v[base + 0] = T0 * q0 + T1 * q1 + T2 * q2 + T3 + tr0;
      out_v[base + 1] = T4 * q0 + T5 * q1 + T6 * q2 + T7 + tr1;
      out_v[base + 2] = T8 * q0 + T9 * q1 + T10 * q2 + T11 + tr2;
    }
  }
}

// ---------------------------------------------------------------------------
extern "C" void kernel_launch(void* const* d_in, const int* in_sizes, int n_in,
                              void* d_out, int out_size, void* d_ws,
                              size_t ws_size, hipStream_t stream) {
  const float* pose       = (const float*)d_in[0];
  const float* betas      = (const float*)d_in[1];
  const float* trans      = (const float*)d_in[2];
  const float* v_template = (const float*)d_in[3];
  const float* shapedirs  = (const float*)d_in[4];
  const float* posedirs   = (const float*)d_in[5];
  const float* Jreg       = (const float*)d_in[6];
  const float* weights    = (const float*)d_in[7];

  float* out = (float*)d_out;
  float* out_v       = out;
  float* out_vposed  = out + (size_t)kB * kD;
  float* out_vshaped = out + 2 * (size_t)kB * kD;
  float* out_Jt      = out + 3 * (size_t)kB * kD;

  float* wsf   = (float*)d_ws;
  float* pfT   = wsf;                   // kNF*kB
  float* Gskin = pfT + kNF * kB;        // kB*288
  float* js    = Gskin + kB * 288;      // 72*10
  float* jt    = js + 72 * kNB;         // 72

  // zero the atomic accumulators (js: 720 floats, jt: 72 floats, contiguous)
  hipMemsetAsync(js, 0, (72 * kNB + 72) * sizeof(float), stream);

  hipLaunchKernelGGL(kA_js, dim3(72, 4), dim3(256), 0, stream, Jreg, shapedirs,
                     v_template, js, jt);
  hipLaunchKernelGGL(kC_batch, dim3(kB), dim3(64), 0, stream, pose, betas,
                     trans, js, jt, pfT, Gskin, out_Jt);
  hipLaunchKernelGGL(k14_fused, dim3((kD + 63) / 64, 16), dim3(256), 0,
                     stream, shapedirs, posedirs, v_template, betas, pfT,
                     out_vshaped, out_vposed);
  hipLaunchKernelGGL(k5_skin, dim3((kV + 255) / 256, 64), dim3(256), 0, stream,
                     weights, Gskin, trans, out_vposed, out_v);
}

// Round 12
// 253.655 us; speedup vs baseline: 2.1323x; 1.5483x over previous
//
#include <hip/hip_runtime.h>

constexpr int kB  = 512;
constexpr int kV  = 6890;
constexpr int kJ  = 24;
constexpr int kD  = kV * 3;   // 20670
constexpr int kNB = 10;
constexpr int kNF = 93;

// ---------------------------------------------------------------------------
// KA v3: batch-independent joint-regressor folding, v-split x4, NO atomics.
// Each y-partition writes its own partial slice jsp[y][72][10] / jtp[y][72];
// kC sums the 4 partials inline (792 floats, L1-trivial). Removes the
// memset dispatch and atomic round-trips of r5-r11's version.
// grid(72,4), block(256).
// ---------------------------------------------------------------------------
__global__ __launch_bounds__(256) void kA_js(
    const float* __restrict__ Jreg, const float* __restrict__ shapedirs,
    const float* __restrict__ v_template, float* __restrict__ jsp,
    float* __restrict__ jtp) {
  int jk = blockIdx.x;
  int j = jk / 3, k = jk % 3;
  int tid = threadIdx.x;
  float acc[kNB];
  float accT = 0.f;
#pragma unroll
  for (int nb = 0; nb < kNB; ++nb) acc[nb] = 0.f;
  for (int v = blockIdx.y * 256 + tid; v < kV; v += 1024) {
    float w = Jreg[(size_t)j * kV + v];
    const float* srow = shapedirs + (size_t)(v * 3 + k) * kNB;
    accT += w * v_template[v * 3 + k];
#pragma unroll
    for (int nb = 0; nb < kNB; ++nb) acc[nb] += w * srow[nb];
  }
#pragma unroll
  for (int nb = 0; nb < kNB; ++nb)
#pragma unroll
    for (int off = 32; off > 0; off >>= 1)
      acc[nb] += __shfl_down(acc[nb], off, 64);
#pragma unroll
  for (int off = 32; off > 0; off >>= 1) accT += __shfl_down(accT, off, 64);
  __shared__ float red[4][11];
  int wave = tid >> 6, lane = tid & 63;
  if (lane == 0) {
#pragma unroll
    for (int nb = 0; nb < kNB; ++nb) red[wave][nb] = acc[nb];
    red[wave][10] = accT;
  }
  __syncthreads();
  if (tid == 0) {
#pragma unroll
    for (int nb = 0; nb < kNB; ++nb)
      jsp[(size_t)blockIdx.y * 720 + jk * kNB + nb] =
          red[0][nb] + red[1][nb] + red[2][nb] + red[3][nb];
    jtp[(size_t)blockIdx.y * 72 + jk] =
        red[0][10] + red[1][10] + red[2][10] + red[3][10];
  }
}

// ---------------------------------------------------------------------------
// KC v2: 4 batches per block (grid 512->128, block 256). Each 64-lane wave
// handles one batch with the r0-proven per-batch code; the 10-syncthreads
// serial chain is amortized over 4x the work per dispatch slot. Sums kA's
// 4 partial js/jt slices inline.
// ---------------------------------------------------------------------------
__global__ __launch_bounds__(256) void kC_batch(
    const float* __restrict__ pose, const float* __restrict__ betas,
    const float* __restrict__ trans, const float* __restrict__ jsp,
    const float* __restrict__ jtp, float* __restrict__ pfT,
    float* __restrict__ Gskin, float* __restrict__ out_Jt) {
  const int parent[24] = {-1, 0, 0, 0, 1, 2, 3, 4, 5, 6, 7, 8,
                          9, 9, 9, 12, 13, 14, 16, 17, 18, 19, 20, 21};
  const int depth[24] = {0, 1, 1, 1, 2, 2, 2, 3, 3, 3, 4, 4,
                         4, 4, 4, 5, 5, 5, 6, 6, 7, 7, 8, 8};
  const int bi = threadIdx.x >> 6;   // batch slot 0..3
  const int j = threadIdx.x & 63;
  const int b = blockIdx.x * 4 + bi;
  __shared__ float G[4][24][12];
  __shared__ float Jp_s[4][24][3];
  float R[9];
  if (j < 24) {
    float t0 = pose[b * 72 + 3 * j + 0];
    float t1 = pose[b * 72 + 3 * j + 1];
    float t2 = pose[b * 72 + 3 * j + 2];
    float a0 = t0 + 1e-8f, a1 = t1 + 1e-8f, a2 = t2 + 1e-8f;
    float angle = sqrtf(a0 * a0 + a1 * a1 + a2 * a2);
    float inv = 1.0f / angle;
    float h = 0.5f * angle;
    float c = cosf(h), s = sinf(h);
    float x = s * t0 * inv, y = s * t1 * inv, z = s * t2 * inv, w = c;
    if (j >= 1) {
      int f = 4 * (j - 1);
      pfT[(size_t)(f + 0) * kB + b] = x;
      pfT[(size_t)(f + 1) * kB + b] = y;
      pfT[(size_t)(f + 2) * kB + b] = z;
      pfT[(size_t)(f + 3) * kB + b] = c - 1.0f;
    } else {
      pfT[(size_t)92 * kB + b] = betas[b * kNB + 1];
    }
    float xx = x * x, yy = y * y, zz = z * z;
    float wx = w * x, wy = w * y, wz = w * z;
    float xy = x * y, xz = x * z, yz = y * z;
    R[0] = 1.f - 2.f * (yy + zz); R[1] = 2.f * (xy - wz); R[2] = 2.f * (xz + wy);
    R[3] = 2.f * (xy + wz); R[4] = 1.f - 2.f * (xx + zz); R[5] = 2.f * (yz - wx);
    R[6] = 2.f * (xz - wy); R[7] = 2.f * (yz + wx); R[8] = 1.f - 2.f * (xx + yy);
    float bet[kNB];
#pragma unroll
    for (int nb = 0; nb < kNB; ++nb) bet[nb] = betas[b * kNB + nb];
#pragma unroll
    for (int k = 0; k < 3; ++k) {
      int jk = j * 3 + k;
      float a = jtp[jk] + jtp[72 + jk] + jtp[144 + jk] + jtp[216 + jk];
#pragma unroll
      for (int nb = 0; nb < kNB; ++nb) {
        float s4 = jsp[jk * kNB + nb] + jsp[720 + jk * kNB + nb] +
                   jsp[1440 + jk * kNB + nb] + jsp[2160 + jk * kNB + nb];
        a += s4 * bet[nb];
      }
      Jp_s[bi][j][k] = a;
    }
  }
  __syncthreads();
  float tl[3];
  if (j < 24) {
    int p = parent[j];
#pragma unroll
    for (int k = 0; k < 3; ++k)
      tl[k] = (p >= 0) ? (Jp_s[bi][j][k] - Jp_s[bi][p][k]) : Jp_s[bi][j][k];
    if (j == 0) {
#pragma unroll
      for (int r = 0; r < 3; ++r) {
        G[bi][0][r * 4 + 0] = R[r * 3 + 0];
        G[bi][0][r * 4 + 1] = R[r * 3 + 1];
        G[bi][0][r * 4 + 2] = R[r * 3 + 2];
        G[bi][0][r * 4 + 3] = tl[r];
      }
    }
  }
  __syncthreads();
  for (int lev = 1; lev <= 8; ++lev) {
    if (j < 24 && depth[j] == lev) {
      int p = parent[j];
      float nG[12];
#pragma unroll
      for (int r = 0; r < 3; ++r) {
        float g0 = G[bi][p][r * 4 + 0], g1 = G[bi][p][r * 4 + 1];
        float g2 = G[bi][p][r * 4 + 2], g3 = G[bi][p][r * 4 + 3];
        nG[r * 4 + 0] = g0 * R[0] + g1 * R[3] + g2 * R[6];
        nG[r * 4 + 1] = g0 * R[1] + g1 * R[4] + g2 * R[7];
        nG[r * 4 + 2] = g0 * R[2] + g1 * R[5] + g2 * R[8];
        nG[r * 4 + 3] = g0 * tl[0] + g1 * tl[1] + g2 * tl[2] + g3;
      }
#pragma unroll
      for (int e = 0; e < 12; ++e) G[bi][j][e] = nG[e];
    }
    __syncthreads();
  }
  if (j < 24) {
    float tr[3];
#pragma unroll
    for (int k = 0; k < 3; ++k) tr[k] = trans[b * 3 + k];
#pragma unroll
    for (int k = 0; k < 3; ++k)
      out_Jt[b * 72 + j * 3 + k] = G[bi][j][k * 4 + 3] + tr[k];
    float jp0 = Jp_s[bi][j][0], jp1 = Jp_s[bi][j][1], jp2 = Jp_s[bi][j][2];
    float* gs = Gskin + b * 288 + j * 12;
#pragma unroll
    for (int r = 0; r < 3; ++r) {
      float t = G[bi][j][r * 4 + 0] * jp0 + G[bi][j][r * 4 + 1] * jp1 +
                G[bi][j][r * 4 + 2] * jp2;
      gs[r * 4 + 0] = G[bi][j][r * 4 + 0];
      gs[r * 4 + 1] = G[bi][j][r * 4 + 1];
      gs[r * 4 + 2] = G[bi][j][r * 4 + 2];
      gs[r * 4 + 3] = G[bi][j][r * 4 + 3] - t;
    }
  }
}

// ---------------------------------------------------------------------------
// K14: fused shape+pose blend — EXACT r0-proven form (~70 us). Thread owns
// one d-row; pd[93]/sd[10] in registers; betas/pfT via wave-uniform scalar
// loads -> SGPRs. Six restructurings (LDS operands r2-r4, ap[32] r9,
// streamed-pd r10, f-split r11) all lost to this form; do not revisit.
// grid(81, 16), block(256).
// ---------------------------------------------------------------------------
__global__ __launch_bounds__(256) void k14_fused(
    const float* __restrict__ shapedirs, const float* __restrict__ posedirs,
    const float* __restrict__ v_template, const float* __restrict__ betas,
    const float* __restrict__ pfT, float* __restrict__ out_vshaped,
    float* __restrict__ out_vposed) {
  int tid = threadIdx.x;
  int d = blockIdx.x * 256 + tid;
  bool active = d < kD;
  int dl = active ? d : (kD - 1);  // clamp for loads
  float sd[kNB], pd[kNF];
#pragma unroll
  for (int k = 0; k < kNB; ++k) sd[k] = shapedirs[(size_t)dl * kNB + k];
#pragma unroll
  for (int f = 0; f < kNF; ++f) pd[f] = posedirs[(size_t)dl * kNF + f];
  float vt = v_template[dl];
  int b0 = blockIdx.y * 32;
#pragma unroll 1
  for (int bc = 0; bc < 4; ++bc) {
    int bb = b0 + bc * 8;
    float as[8], ap[8];
#pragma unroll
    for (int t = 0; t < 8; ++t) {
      const float* be = betas + (size_t)(bb + t) * kNB;  // wave-uniform
      float a = vt;
#pragma unroll
      for (int k = 0; k < kNB; ++k) a += sd[k] * be[k];
      as[t] = a;
      ap[t] = a;
    }
#pragma unroll
    for (int f = 0; f < kNF; ++f) {
      float pdf = pd[f];
      const float* q = pfT + (size_t)f * kB + bb;  // wave-uniform
#pragma unroll
      for (int t = 0; t < 8; ++t) ap[t] += pdf * q[t];
    }
    if (active) {
#pragma unroll
      for (int t = 0; t < 8; ++t) {
        size_t idx = (size_t)(bb + t) * kD + d;
        out_vshaped[idx] = as[t];
        out_vposed[idx] = ap[t];
      }
    }
  }
}

// ---------------------------------------------------------------------------
// K5 v3 (r7-proven, 77 -> <74 us): LBS skinning with LDS-staged Gskin.
// 8 batches of Gskin (9.2 KB) staged coalesced once per block; j-loop feeds
// from ds_read_b128 broadcasts. Live set ~60 floats -> no allocator
// pathology. vposed prefetched before the j-loop. grid(27, 64), block(256).
// ---------------------------------------------------------------------------
__global__ __launch_bounds__(256) void k5_skin(
    const float* __restrict__ weights, const float* __restrict__ Gskin,
    const float* __restrict__ trans, const float* __restrict__ vposed,
    float* __restrict__ out_v) {
  __shared__ __align__(16) float Gs[8 * 288];  // 9216 B
  int tid = threadIdx.x;
  int v = blockIdx.x * 256 + tid;
  bool active = v < kV;
  int vl = active ? v : (kV - 1);
  float w[kJ];
#pragma unroll
  for (int j = 0; j < kJ; ++j) w[j] = weights[(size_t)vl * kJ + j];
  int b0 = blockIdx.y * 8;
  {
    const float* src = Gskin + (size_t)b0 * 288;
#pragma unroll
    for (int i = 0; i < 9; ++i) Gs[i * 256 + tid] = src[i * 256 + tid];
  }
  __syncthreads();
#pragma unroll 1
  for (int bi = 0; bi < 8; ++bi) {
    int b = b0 + bi;
    size_t base = (size_t)b * kD + (size_t)vl * 3;
    float q0 = vposed[base + 0];
    float q1 = vposed[base + 1];
    float q2 = vposed[base + 2];
    float tr0 = trans[b * 3 + 0];
    float tr1 = trans[b * 3 + 1];
    float tr2 = trans[b * 3 + 2];
    const float4* Gt = (const float4*)(Gs + bi * 288);
    float T0 = 0.f, T1 = 0.f, T2 = 0.f, T3 = 0.f;
    float T4 = 0.f, T5 = 0.f, T6 = 0.f, T7 = 0.f;
    float T8 = 0.f, T9 = 0.f, T10 = 0.f, T11 = 0.f;
#pragma unroll 4
    for (int j = 0; j < kJ; ++j) {
      float wj = w[j];
      float4 ga = Gt[j * 3 + 0];  // broadcast ds_read_b128
      float4 gb = Gt[j * 3 + 1];
      float4 gc = Gt[j * 3 + 2];
      T0 += wj * ga.x; T1 += wj * ga.y; T2 += wj * ga.z; T3 += wj * ga.w;
      T4 += wj * gb.x; T5 += wj * gb.y; T6 += wj * gb.z; T7 += wj * gb.w;
      T8 += wj * gc.x; T9 += wj * gc.y; T10 += wj * gc.z; T11 += wj * gc.w;
    }
    if (active) {
      out_v[base + 0] = T0 * q0 + T1 * q1 + T2 * q2 + T3 + tr0;
      out_v[base + 1] = T4 * q0 + T5 * q1 + T6 * q2 + T7 + tr1;
      out_v[base + 2] = T8 * q0 + T9 * q1 + T10 * q2 + T11 + tr2;
    }
  }
}

// ---------------------------------------------------------------------------
extern "C" void kernel_launch(void* const* d_in, const int* in_sizes, int n_in,
                              void* d_out, int out_size, void* d_ws,
                              size_t ws_size, hipStream_t stream) {
  const float* pose       = (const float*)d_in[0];
  const float* betas      = (const float*)d_in[1];
  const float* trans      = (const float*)d_in[2];
  const float* v_template = (const float*)d_in[3];
  const float* shapedirs  = (const float*)d_in[4];
  const float* posedirs   = (const float*)d_in[5];
  const float* Jreg       = (const float*)d_in[6];
  const float* weights    = (const float*)d_in[7];

  float* out = (float*)d_out;
  float* out_v       = out;
  float* out_vposed  = out + (size_t)kB * kD;
  float* out_vshaped = out + 2 * (size_t)kB * kD;
  float* out_Jt      = out + 3 * (size_t)kB * kD;

  float* wsf   = (float*)d_ws;
  float* pfT   = wsf;                   // kNF*kB
  float* Gskin = pfT + kNF * kB;        // kB*288
  float* jsp   = Gskin + kB * 288;      // 4*72*10
  float* jtp   = jsp + 4 * 720;         // 4*72

  hipLaunchKernelGGL(kA_js, dim3(72, 4), dim3(256), 0, stream, Jreg, shapedirs,
                     v_template, jsp, jtp);
  hipLaunchKernelGGL(kC_batch, dim3(kB / 4), dim3(256), 0, stream, pose, betas,
                     trans, jsp, jtp, pfT, Gskin, out_Jt);
  hipLaunchKernelGGL(k14_fused, dim3((kD + 255) / 256, 16), dim3(256), 0,
                     stream, shapedirs, posedirs, v_template, betas, pfT,
                     out_vshaped, out_vposed);
  hipLaunchKernelGGL(k5_skin, dim3((kV + 255) / 256, 64), dim3(256), 0, stream,
                     weights, Gskin, trans, out_vposed, out_v);
}